// Round 1
// baseline (630.018 us; speedup 1.0000x reference)
//
#include <hip/hip_runtime.h>
#include <math.h>

#define DIMC   256
#define NQ     4096
#define BATCH  4
#define HG     32      // H/SR
#define WG     32      // W/SR
#define NS     1024    // HG*WG
#define NHEADS 8
#define HDIM   32
#define KCHUNK 128
#define SCALE_ATTN 0.17677669529663687f  // 32^-0.5

// ---------------- scatter: token2map segment-sum ----------------
__global__ __launch_bounds__(DIMC) void scatter_kernel(
    const float* __restrict__ xsrc, const float* __restrict__ loc,
    const float* __restrict__ csrc, float* __restrict__ feat,
    float* __restrict__ cnt, float* __restrict__ confsum)
{
    int token = blockIdx.x;          // B*NQ tokens
    int b = token >> 12;             // NQ = 4096
    int c = threadIdx.x;
    float lx = loc[token * 2 + 0];
    float ly = loc[token * 2 + 1];
    lx = fminf(fmaxf(lx, 0.f), 1.f) * (float)(WG - 1);
    ly = fminf(fmaxf(ly, 0.f), 1.f) * (float)(HG - 1);
    int ix = (int)rintf(lx);         // rintf = round-half-even, matches jnp.round
    int iy = (int)rintf(ly);
    int cell = b * NS + iy * WG + ix;
    atomicAdd(&feat[cell * DIMC + c], xsrc[token * DIMC + c]);
    if (c == 0) {
        atomicAdd(&cnt[cell], 1.f);
        atomicAdd(&confsum[cell], csrc[token]);
    }
}

// ---------------- finalize: feat /= (cnt+eps), mask; conf map ----------------
__global__ __launch_bounds__(DIMC) void featfin_kernel(
    const float* __restrict__ cnt, const float* __restrict__ confsum,
    float* __restrict__ feat, float* __restrict__ conf)
{
    int m = blockIdx.x;              // B*NS cells
    int c = threadIdx.x;
    float cv = cnt[m];
    float inv = (cv > 0.f) ? 1.f / (cv + 1e-6f) : 0.f;
    feat[m * DIMC + c] *= inv;
    if (c == 0) conf[m] = confsum[m] * inv;
}

// ---------------- tiled row-GEMM: out[r][c] = bias[c] + dot(A[r], W[c]) ----------------
template <bool HASBIAS>
__global__ __launch_bounds__(DIMC) void rowgemm16_kernel(
    const float* __restrict__ A, const float* __restrict__ W,
    const float* __restrict__ bias, float* __restrict__ out)
{
    __shared__ float As[16][DIMC];
    int r0 = blockIdx.x * 16;
    int c = threadIdx.x;
    #pragma unroll
    for (int i = 0; i < 16; i++) As[i][c] = A[(size_t)(r0 + i) * DIMC + c];
    __syncthreads();
    float acc[16];
    float bv = HASBIAS ? bias[c] : 0.f;
    #pragma unroll
    for (int i = 0; i < 16; i++) acc[i] = bv;
    const float* wr = W + (size_t)c * DIMC;
    for (int j = 0; j < DIMC; j += 4) {
        float4 w4 = *(const float4*)(wr + j);
        #pragma unroll
        for (int i = 0; i < 16; i++) {
            float4 a4 = *(const float4*)(&As[i][j]);
            acc[i] += a4.x * w4.x + a4.y * w4.y + a4.z * w4.z + a4.w * w4.w;
        }
    }
    #pragma unroll
    for (int i = 0; i < 16; i++) out[(size_t)(r0 + i) * DIMC + c] = acc[i];
}

// ---------------- layernorm in place over last dim ----------------
__global__ __launch_bounds__(DIMC) void ln_kernel(
    float* __restrict__ xs, const float* __restrict__ g, const float* __restrict__ b)
{
    int m = blockIdx.x;
    int c = threadIdx.x;
    float v = xs[(size_t)m * DIMC + c];
    float s = v, q = v * v;
    #pragma unroll
    for (int off = 32; off > 0; off >>= 1) {
        s += __shfl_xor(s, off);
        q += __shfl_xor(q, off);
    }
    __shared__ float sh1[4], sh2[4];
    int wid = c >> 6, lane = c & 63;
    if (lane == 0) { sh1[wid] = s; sh2[wid] = q; }
    __syncthreads();
    s = sh1[0] + sh1[1] + sh1[2] + sh1[3];
    q = sh2[0] + sh2[1] + sh2[2] + sh2[3];
    float mu  = s * (1.f / DIMC);
    float var = q * (1.f / DIMC) - mu * mu;
    xs[(size_t)m * DIMC + c] = (v - mu) * rsqrtf(var + 1e-5f) * g[c] + b[c];
}

// ---------------- flash attention over NS=1024 keys, conf bias per key ----------------
__global__ __launch_bounds__(256) void attn_kernel(
    const float* __restrict__ qbuf, const float* __restrict__ kbuf,
    const float* __restrict__ vbuf, const float* __restrict__ conf,
    float* __restrict__ abuf)
{
    __shared__ float ks[KCHUNK * HDIM];
    __shared__ float vs[KCHUNK * HDIM];
    __shared__ float cs[KCHUNK];
    int blk  = blockIdx.x;           // B*NHEADS*(NQ/256)
    int tile = blk & 15;             // NQ/256 = 16
    int bh   = blk >> 4;
    int hh   = bh & (NHEADS - 1);
    int b    = bh >> 3;
    int n    = tile * 256 + threadIdx.x;

    const float* qrow = qbuf + ((size_t)(b * NQ + n)) * DIMC + hh * HDIM;
    float qv[HDIM];
    #pragma unroll
    for (int d = 0; d < HDIM; d += 4) {
        float4 t = *(const float4*)(qrow + d);
        qv[d] = t.x; qv[d + 1] = t.y; qv[d + 2] = t.z; qv[d + 3] = t.w;
    }
    float acc[HDIM];
    #pragma unroll
    for (int d = 0; d < HDIM; d++) acc[d] = 0.f;
    float mval = -INFINITY, l = 0.f;

    const float* kbase = kbuf + (size_t)b * NS * DIMC + hh * HDIM;
    const float* vbase = vbuf + (size_t)b * NS * DIMC + hh * HDIM;

    for (int m0 = 0; m0 < NS; m0 += KCHUNK) {
        __syncthreads();
        for (int i = threadIdx.x; i < KCHUNK * HDIM / 4; i += 256) {
            int row = i >> 3, q4 = i & 7;
            ((float4*)ks)[i] = *(const float4*)(kbase + (size_t)(m0 + row) * DIMC + q4 * 4);
            ((float4*)vs)[i] = *(const float4*)(vbase + (size_t)(m0 + row) * DIMC + q4 * 4);
        }
        if (threadIdx.x < KCHUNK) cs[threadIdx.x] = conf[b * NS + m0 + threadIdx.x];
        __syncthreads();
        for (int mm = 0; mm < KCHUNK; mm++) {
            const float* kr = ks + mm * HDIM;
            float dot = 0.f;
            #pragma unroll
            for (int d = 0; d < HDIM; d++) dot += qv[d] * kr[d];
            float logit = dot * SCALE_ATTN + cs[mm];
            const float* vr = vs + mm * HDIM;
            if (logit <= mval) {
                float e = __expf(logit - mval);
                l += e;
                #pragma unroll
                for (int d = 0; d < HDIM; d++) acc[d] += e * vr[d];
            } else {
                float corr = __expf(mval - logit);   // exp(-inf)=0 on first key
                l = l * corr + 1.f;
                #pragma unroll
                for (int d = 0; d < HDIM; d++) acc[d] = acc[d] * corr + vr[d];
                mval = logit;
            }
        }
    }
    float invl = 1.f / l;
    float* orow = abuf + ((size_t)(b * NQ + n)) * DIMC + hh * HDIM;
    #pragma unroll
    for (int d = 0; d < HDIM; d += 4) {
        float4 t;
        t.x = acc[d] * invl; t.y = acc[d + 1] * invl;
        t.z = acc[d + 2] * invl; t.w = acc[d + 3] * invl;
        *(float4*)(orow + d) = t;
    }
}

extern "C" void kernel_launch(void* const* d_in, const int* in_sizes, int n_in,
                              void* d_out, int out_size, void* d_ws, size_t ws_size,
                              hipStream_t stream)
{
    (void)in_sizes; (void)n_in; (void)out_size; (void)ws_size;
    const float* x    = (const float*)d_in[0];
    const float* xsrc = (const float*)d_in[1];
    const float* loc  = (const float*)d_in[2];
    const float* csrc = (const float*)d_in[3];
    const float* Wq   = (const float*)d_in[4];
    const float* Wk   = (const float*)d_in[5];
    const float* Wv   = (const float*)d_in[6];
    const float* Wsr  = (const float*)d_in[7];
    const float* bsr  = (const float*)d_in[8];
    const float* lng  = (const float*)d_in[9];
    const float* lnb  = (const float*)d_in[10];
    const float* Wp   = (const float*)d_in[11];
    const float* bp   = (const float*)d_in[12];
    // d_in[13]=H(64), d_in[14]=W(64): fixed by setup_inputs; h=w=32 hardcoded.

    float* ws      = (float*)d_ws;
    float* feat    = ws;                          // B*NS*C = 1,048,576
    float* cnt     = feat    + BATCH * NS * DIMC; // 4096
    float* confsum = cnt     + BATCH * NS;        // 4096
    float* conf    = confsum + BATCH * NS;        // 4096
    float* xs      = conf    + BATCH * NS;        // 1,048,576
    float* kbuf    = xs      + BATCH * NS * DIMC; // 1,048,576
    float* vbuf    = kbuf    + BATCH * NS * DIMC; // 1,048,576
    float* qbuf    = vbuf    + BATCH * NS * DIMC; // 4,194,304
    float* abuf    = qbuf    + BATCH * NQ * DIMC; // 4,194,304
    float* outp    = (float*)d_out;               // total ws use ≈ 50.4 MB

    hipMemsetAsync(feat, 0,
        (size_t)(BATCH * NS * DIMC + 2 * BATCH * NS) * sizeof(float), stream);

    scatter_kernel<<<BATCH * NQ, DIMC, 0, stream>>>(xsrc, loc, csrc, feat, cnt, confsum);
    featfin_kernel<<<BATCH * NS, DIMC, 0, stream>>>(cnt, confsum, feat, conf);
    rowgemm16_kernel<true ><<<BATCH * NS / 16, DIMC, 0, stream>>>(feat, Wsr, bsr, xs);
    ln_kernel<<<BATCH * NS, DIMC, 0, stream>>>(xs, lng, lnb);
    rowgemm16_kernel<false><<<BATCH * NS / 16, DIMC, 0, stream>>>(xs, Wk, nullptr, kbuf);
    rowgemm16_kernel<false><<<BATCH * NS / 16, DIMC, 0, stream>>>(xs, Wv, nullptr, vbuf);
    rowgemm16_kernel<false><<<BATCH * NQ / 16, DIMC, 0, stream>>>(x, Wq, nullptr, qbuf);
    attn_kernel<<<BATCH * NHEADS * (NQ / 256), 256, 0, stream>>>(qbuf, kbuf, vbuf, conf, abuf);
    rowgemm16_kernel<true ><<<BATCH * NQ / 16, DIMC, 0, stream>>>(abuf, Wp, bp, outp);
}

// Round 2
// 414.081 us; speedup vs baseline: 1.5215x; 1.5215x over previous
//
#include <hip/hip_runtime.h>
#include <math.h>

#define DIMC   256
#define NQ     4096
#define BATCH  4
#define NS     1024    // (H/SR)*(W/SR) = 32*32
#define WG     32
#define HG     32
#define NHEADS 8
#define HDIM   32
#define SCALE_ATTN 0.17677669529663687f  // 32^-0.5

typedef __attribute__((ext_vector_type(8))) __bf16 bf16x8;
typedef __attribute__((ext_vector_type(4))) float  f32x4;

#define MFMA16(A, B, C) __builtin_amdgcn_mfma_f32_16x16x32_bf16((A), (B), (C), 0, 0, 0)

// ---------------- scatter: token2map segment-sum ----------------
__global__ __launch_bounds__(DIMC) void scatter_kernel(
    const float* __restrict__ xsrc, const float* __restrict__ loc,
    const float* __restrict__ csrc, float* __restrict__ feat,
    float* __restrict__ cnt, float* __restrict__ confsum)
{
    int token = blockIdx.x;          // B*NQ tokens
    int b = token >> 12;             // NQ = 4096
    int c = threadIdx.x;
    float lx = loc[token * 2 + 0];
    float ly = loc[token * 2 + 1];
    lx = fminf(fmaxf(lx, 0.f), 1.f) * (float)(WG - 1);
    ly = fminf(fmaxf(ly, 0.f), 1.f) * (float)(HG - 1);
    int ix = (int)rintf(lx);         // round-half-even, matches jnp.round
    int iy = (int)rintf(ly);
    int cell = b * NS + iy * WG + ix;
    atomicAdd(&feat[cell * DIMC + c], xsrc[token * DIMC + c]);
    if (c == 0) {
        atomicAdd(&cnt[cell], 1.f);
        atomicAdd(&confsum[cell], csrc[token]);
    }
}

// ---------------- finalize: feat /= (cnt+eps), mask; conf map ----------------
__global__ __launch_bounds__(DIMC) void featfin_kernel(
    const float* __restrict__ cnt, const float* __restrict__ confsum,
    float* __restrict__ feat, float* __restrict__ conf)
{
    int m = blockIdx.x;              // B*NS cells
    int c = threadIdx.x;
    float cv = cnt[m];
    float inv = (cv > 0.f) ? 1.f / (cv + 1e-6f) : 0.f;
    feat[m * DIMC + c] *= inv;
    if (c == 0) conf[m] = confsum[m] * inv;
}

// ---------------- tiled row-GEMM: out[r][c] = bias[c] + dot(A[r], W[c]) ----------------
template <bool HASBIAS>
__global__ __launch_bounds__(DIMC) void rowgemm16_kernel(
    const float* __restrict__ A, const float* __restrict__ W,
    const float* __restrict__ bias, float* __restrict__ out)
{
    __shared__ float As[16][DIMC];
    int r0 = blockIdx.x * 16;
    int c = threadIdx.x;
    #pragma unroll
    for (int i = 0; i < 16; i++) As[i][c] = A[(size_t)(r0 + i) * DIMC + c];
    __syncthreads();
    float acc[16];
    float bv = HASBIAS ? bias[c] : 0.f;
    #pragma unroll
    for (int i = 0; i < 16; i++) acc[i] = bv;
    const float* wr = W + (size_t)c * DIMC;
    for (int j = 0; j < DIMC; j += 4) {
        float4 w4 = *(const float4*)(wr + j);
        #pragma unroll
        for (int i = 0; i < 16; i++) {
            float4 a4 = *(const float4*)(&As[i][j]);
            acc[i] += a4.x * w4.x + a4.y * w4.y + a4.z * w4.z + a4.w * w4.w;
        }
    }
    #pragma unroll
    for (int i = 0; i < 16; i++) out[(size_t)(r0 + i) * DIMC + c] = acc[i];
}

// ---------------- layernorm in place over last dim ----------------
__global__ __launch_bounds__(DIMC) void ln_kernel(
    float* __restrict__ xs, const float* __restrict__ g, const float* __restrict__ b)
{
    int m = blockIdx.x;
    int c = threadIdx.x;
    float v = xs[(size_t)m * DIMC + c];
    float s = v, q = v * v;
    #pragma unroll
    for (int off = 32; off > 0; off >>= 1) {
        s += __shfl_xor(s, off);
        q += __shfl_xor(q, off);
    }
    __shared__ float sh1[4], sh2[4];
    int wid = c >> 6, lane = c & 63;
    if (lane == 0) { sh1[wid] = s; sh2[wid] = q; }
    __syncthreads();
    s = sh1[0] + sh1[1] + sh1[2] + sh1[3];
    q = sh2[0] + sh2[1] + sh2[2] + sh2[3];
    float mu  = s * (1.f / DIMC);
    float var = q * (1.f / DIMC) - mu * mu;
    xs[(size_t)m * DIMC + c] = (v - mu) * rsqrtf(var + 1e-5f) * g[c] + b[c];
}

// ---------------- K split: fp32 -> bf16 hi + bf16 lo (row-major) ----------------
__global__ __launch_bounds__(256) void ksplit_kernel(
    const float* __restrict__ kbuf, unsigned short* __restrict__ khi,
    unsigned short* __restrict__ klo)
{
    int i = blockIdx.x * 256 + threadIdx.x;    // over B*NS*C/2 float2
    float2 v = ((const float2*)kbuf)[i];
    __bf16 h0 = (__bf16)v.x;
    __bf16 h1 = (__bf16)v.y;
    __bf16 l0 = (__bf16)(v.x - (float)h0);
    __bf16 l1 = (__bf16)(v.y - (float)h1);
    unsigned hw = (unsigned)__builtin_bit_cast(unsigned short, h0)
                | ((unsigned)__builtin_bit_cast(unsigned short, h1) << 16);
    unsigned lw = (unsigned)__builtin_bit_cast(unsigned short, l0)
                | ((unsigned)__builtin_bit_cast(unsigned short, l1) << 16);
    ((unsigned*)khi)[i] = hw;
    ((unsigned*)klo)[i] = lw;
}

// ---------------- V transpose + split: vbuf[B*NS][C] -> vt[B*H*32][NS] hi/lo ----------------
__global__ __launch_bounds__(256) void vtrans_kernel(
    const float* __restrict__ vbuf, unsigned short* __restrict__ vthi,
    unsigned short* __restrict__ vtlo)
{
    __shared__ float tile[32][DIMC + 1];       // [key][c], padded: ~33 KB
    int blk = blockIdx.x;                      // B * (NS/32)
    int b  = blk >> 5;
    int k0 = (blk & 31) * 32;
    int t = threadIdx.x;
    for (int r = 0; r < 32; r++)
        tile[r][t] = vbuf[((size_t)(b * NS + k0 + r)) * DIMC + t];
    __syncthreads();
    int key = t & 31, c0 = t >> 5;             // 8 c-groups x 32 keys
    for (int i = 0; i < 32; i++) {
        int c = c0 * 32 + i;                   // c = h*32 + d
        float v = tile[key][c];
        __bf16 h = (__bf16)v;
        __bf16 l = (__bf16)(v - (float)h);
        size_t off = ((size_t)(b * DIMC + c)) * NS + k0 + key;  // row = (b*8+h)*32+d
        vthi[off] = __builtin_bit_cast(unsigned short, h);
        vtlo[off] = __builtin_bit_cast(unsigned short, l);
    }
}

// ---------------- MFMA flash attention (bf16x2 split, swapped-operand) ----------------
// Wave owns 32 queries (2 col-frags of 16). Per 32-key chunk:
//   S^T[key][q] = (Khi+Klo)(Qhi+Qlo)^T via 3 mfmas/frag-pair  (lane: q=l&15, keys 4g+r)
//   online softmax: reduce over keys = 8 local + shfl_xor(16,32)
//   P -> bf16 hi/lo, ds_bpermute into PV B-operand layout
//   O^T[d][q] += Vt^T * P^T via 3 mfmas per d-frag
__global__ __launch_bounds__(256) void attn_mfma_kernel(
    const float* __restrict__ qbuf,
    const unsigned short* __restrict__ khi, const unsigned short* __restrict__ klo,
    const unsigned short* __restrict__ vthi, const unsigned short* __restrict__ vtlo,
    const float* __restrict__ conf, float* __restrict__ abuf)
{
    int blk  = blockIdx.x;            // B*H*(NQ/128) = 1024
    int qt   = blk & 31;              // NQ/128 = 32
    int bh   = blk >> 5;
    int hh   = bh & (NHEADS - 1);
    int b    = bh >> 3;
    int wave = threadIdx.x >> 6;
    int lane = threadIdx.x & 63;
    int s = lane & 15, g = lane >> 4;
    int q0 = qt * 128 + wave * 32;

    // ---- Q fragments (B-operand for S^T): lane holds Q[q0+qf*16+s][d=8g+j] ----
    bf16x8 qh[2], ql[2];
    #pragma unroll
    for (int qf = 0; qf < 2; qf++) {
        const float* qp = qbuf + ((size_t)(b * NQ + q0 + qf * 16 + s)) * DIMC + hh * HDIM + 8 * g;
        float4 a = *(const float4*)qp;
        float4 c = *(const float4*)(qp + 4);
        float qv[8] = {a.x, a.y, a.z, a.w, c.x, c.y, c.z, c.w};
        #pragma unroll
        for (int j = 0; j < 8; j++) {
            __bf16 hi = (__bf16)qv[j];
            qh[qf][j] = hi;
            ql[qf][j] = (__bf16)(qv[j] - (float)hi);
        }
    }

    f32x4 oacc[2][2];
    #pragma unroll
    for (int qf = 0; qf < 2; qf++)
        #pragma unroll
        for (int m = 0; m < 2; m++)
            oacc[qf][m] = (f32x4){0.f, 0.f, 0.f, 0.f};
    float mrun[2] = {-INFINITY, -INFINITY};
    float lrun[2] = {0.f, 0.f};

    const unsigned short* khb = khi + ((size_t)(b * NS)) * DIMC + hh * HDIM + 8 * g;
    const unsigned short* klb = klo + ((size_t)(b * NS)) * DIMC + hh * HDIM + 8 * g;
    const unsigned short* vhb = vthi + ((size_t)(bh * HDIM)) * NS + 8 * g;
    const unsigned short* vlb = vtlo + ((size_t)(bh * HDIM)) * NS + 8 * g;
    const float* cfb = conf + b * NS + 4 * g;

    int addr0 = (s + ((g & 1) << 5)) << 2;   // src lane s + 32*(g&1), bytes
    int addr1 = addr0 + 64;                  // +16 lanes
    bool hiHalf = (g >= 2);                  // source frag = g>>1

    for (int k0 = 0; k0 < NS; k0 += 32) {
        // K fragments (A-operand): lane holds K[k0+16f+s][d=8g+j]
        bf16x8 kh[2], kl[2];
        #pragma unroll
        for (int f = 0; f < 2; f++) {
            size_t roff = ((size_t)(k0 + 16 * f + s)) * DIMC;
            kh[f] = *(const bf16x8*)(khb + roff);
            kl[f] = *(const bf16x8*)(klb + roff);
        }
        // V^T fragments (A-operand for PV): lane holds Vt[16m+s][k0+8g+j]
        bf16x8 vh[2], vl[2];
        #pragma unroll
        for (int m = 0; m < 2; m++) {
            size_t off = ((size_t)(16 * m + s)) * NS + k0;
            vh[m] = *(const bf16x8*)(vhb + off);
            vl[m] = *(const bf16x8*)(vlb + off);
        }
        // conf for this lane's score slots: keys k0 + 16f + 4g + r
        float cv[2][4];
        #pragma unroll
        for (int f = 0; f < 2; f++)
            #pragma unroll
            for (int r = 0; r < 4; r++)
                cv[f][r] = cfb[k0 + 16 * f + r];

        #pragma unroll
        for (int qf = 0; qf < 2; qf++) {
            // S^T = K * Q^T (3 split products)
            f32x4 sa[2];
            #pragma unroll
            for (int f = 0; f < 2; f++) {
                f32x4 z = (f32x4){0.f, 0.f, 0.f, 0.f};
                z = MFMA16(kh[f], qh[qf], z);
                z = MFMA16(kh[f], ql[qf], z);
                z = MFMA16(kl[f], qh[qf], z);
                sa[f] = z;
            }
            // scores + online softmax (per lane: 8 keys for query s)
            float sc[2][4], mc = -INFINITY;
            #pragma unroll
            for (int f = 0; f < 2; f++)
                #pragma unroll
                for (int r = 0; r < 4; r++) {
                    sc[f][r] = sa[f][r] * SCALE_ATTN + cv[f][r];
                    mc = fmaxf(mc, sc[f][r]);
                }
            mc = fmaxf(mc, __shfl_xor(mc, 16));
            mc = fmaxf(mc, __shfl_xor(mc, 32));
            float mnew = fmaxf(mrun[qf], mc);
            float corr = __expf(mrun[qf] - mnew);   // exp(-inf)=0 first chunk
            mrun[qf] = mnew;
            float p[2][4], ls = 0.f;
            #pragma unroll
            for (int f = 0; f < 2; f++)
                #pragma unroll
                for (int r = 0; r < 4; r++) {
                    p[f][r] = __expf(sc[f][r] - mnew);
                    ls += p[f][r];
                }
            ls += __shfl_xor(ls, 16);
            ls += __shfl_xor(ls, 32);
            lrun[qf] = lrun[qf] * corr + ls;
            #pragma unroll
            for (int m = 0; m < 2; m++)
                #pragma unroll
                for (int r = 0; r < 4; r++)
                    oacc[qf][m][r] *= corr;

            // P -> bf16 hi/lo packed words: whi[f][r2] = keys {16f+4g+2r2, +1}
            unsigned whi[2][2], wlo[2][2];
            #pragma unroll
            for (int f = 0; f < 2; f++)
                #pragma unroll
                for (int r2 = 0; r2 < 2; r2++) {
                    float p0 = p[f][2 * r2], p1 = p[f][2 * r2 + 1];
                    __bf16 h0 = (__bf16)p0, h1 = (__bf16)p1;
                    __bf16 l0 = (__bf16)(p0 - (float)h0), l1 = (__bf16)(p1 - (float)h1);
                    whi[f][r2] = (unsigned)__builtin_bit_cast(unsigned short, h0)
                               | ((unsigned)__builtin_bit_cast(unsigned short, h1) << 16);
                    wlo[f][r2] = (unsigned)__builtin_bit_cast(unsigned short, l0)
                               | ((unsigned)__builtin_bit_cast(unsigned short, l1) << 16);
                }
            // gather to PV B-operand: lane gets P^T[key=8g+2j,2j+1][q=s]
            unsigned bwh[4], bwl[4];
            {
                int a0h = __builtin_amdgcn_ds_bpermute(addr0, (int)whi[0][0]);
                int a0h1 = __builtin_amdgcn_ds_bpermute(addr0, (int)whi[1][0]);
                bwh[0] = (unsigned)(hiHalf ? a0h1 : a0h);
                int a1h = __builtin_amdgcn_ds_bpermute(addr0, (int)whi[0][1]);
                int a1h1 = __builtin_amdgcn_ds_bpermute(addr0, (int)whi[1][1]);
                bwh[1] = (unsigned)(hiHalf ? a1h1 : a1h);
                int a2h = __builtin_amdgcn_ds_bpermute(addr1, (int)whi[0][0]);
                int a2h1 = __builtin_amdgcn_ds_bpermute(addr1, (int)whi[1][0]);
                bwh[2] = (unsigned)(hiHalf ? a2h1 : a2h);
                int a3h = __builtin_amdgcn_ds_bpermute(addr1, (int)whi[0][1]);
                int a3h1 = __builtin_amdgcn_ds_bpermute(addr1, (int)whi[1][1]);
                bwh[3] = (unsigned)(hiHalf ? a3h1 : a3h);
                int b0 = __builtin_amdgcn_ds_bpermute(addr0, (int)wlo[0][0]);
                int b0h = __builtin_amdgcn_ds_bpermute(addr0, (int)wlo[1][0]);
                bwl[0] = (unsigned)(hiHalf ? b0h : b0);
                int b1 = __builtin_amdgcn_ds_bpermute(addr0, (int)wlo[0][1]);
                int b1h = __builtin_amdgcn_ds_bpermute(addr0, (int)wlo[1][1]);
                bwl[1] = (unsigned)(hiHalf ? b1h : b1);
                int b2 = __builtin_amdgcn_ds_bpermute(addr1, (int)wlo[0][0]);
                int b2h = __builtin_amdgcn_ds_bpermute(addr1, (int)wlo[1][0]);
                bwl[2] = (unsigned)(hiHalf ? b2h : b2);
                int b3 = __builtin_amdgcn_ds_bpermute(addr1, (int)wlo[0][1]);
                int b3h = __builtin_amdgcn_ds_bpermute(addr1, (int)wlo[1][1]);
                bwl[3] = (unsigned)(hiHalf ? b3h : b3);
            }
            union { unsigned u[4]; bf16x8 v; } Bh, Bl;
            #pragma unroll
            for (int j = 0; j < 4; j++) { Bh.u[j] = bwh[j]; Bl.u[j] = bwl[j]; }
            // O^T += V^T * P^T (3 split products per d-frag)
            #pragma unroll
            for (int m = 0; m < 2; m++) {
                oacc[qf][m] = MFMA16(vh[m], Bh.v, oacc[qf][m]);
                oacc[qf][m] = MFMA16(vl[m], Bh.v, oacc[qf][m]);
                oacc[qf][m] = MFMA16(vh[m], Bl.v, oacc[qf][m]);
            }
        } // qf
    } // chunk

    // epilogue: oacc[qf][m][r] = O^T[d=16m+4g+r][q=q0+16qf+s]
    #pragma unroll
    for (int qf = 0; qf < 2; qf++) {
        float invl = 1.f / lrun[qf];
        float* orow = abuf + ((size_t)(b * NQ + q0 + qf * 16 + s)) * DIMC + hh * HDIM;
        #pragma unroll
        for (int m = 0; m < 2; m++) {
            float4 o;
            o.x = oacc[qf][m][0] * invl;
            o.y = oacc[qf][m][1] * invl;
            o.z = oacc[qf][m][2] * invl;
            o.w = oacc[qf][m][3] * invl;
            *(float4*)(orow + 16 * m + 4 * g) = o;
        }
    }
}

extern "C" void kernel_launch(void* const* d_in, const int* in_sizes, int n_in,
                              void* d_out, int out_size, void* d_ws, size_t ws_size,
                              hipStream_t stream)
{
    (void)in_sizes; (void)n_in; (void)out_size; (void)ws_size;
    const float* x    = (const float*)d_in[0];
    const float* xsrc = (const float*)d_in[1];
    const float* loc  = (const float*)d_in[2];
    const float* csrc = (const float*)d_in[3];
    const float* Wq   = (const float*)d_in[4];
    const float* Wk   = (const float*)d_in[5];
    const float* Wv   = (const float*)d_in[6];
    const float* Wsr  = (const float*)d_in[7];
    const float* bsr  = (const float*)d_in[8];
    const float* lng  = (const float*)d_in[9];
    const float* lnb  = (const float*)d_in[10];
    const float* Wp   = (const float*)d_in[11];
    const float* bp   = (const float*)d_in[12];
    // d_in[13]=H(64), d_in[14]=W(64): fixed by setup_inputs; h=w=32 hardcoded.

    const int MS = BATCH * NS * DIMC;     // 1,048,576
    const int MQ = BATCH * NQ * DIMC;     // 4,194,304
    float* ws      = (float*)d_ws;
    // region A (4M floats): feat/xs/kbuf/vbuf, later reused as abuf
    float* feat    = ws;
    float* xs      = feat + MS;
    float* kbuf    = xs   + MS;
    float* vbuf    = kbuf + MS;
    float* abuf    = ws;                  // alias: feat..vbuf dead by attention
    float* qbuf    = ws + 4 * (size_t)MS; // 4M floats
    float* cnt     = qbuf + MQ;
    float* confsum = cnt + BATCH * NS;
    float* conf    = confsum + BATCH * NS;
    unsigned short* khi  = (unsigned short*)(conf + BATCH * NS);
    unsigned short* klo  = khi  + MS;
    unsigned short* vthi = klo  + MS;
    unsigned short* vtlo = vthi + MS;     // total ~40.1 MB
    float* outp    = (float*)d_out;

    hipMemsetAsync(feat, 0, (size_t)MS * sizeof(float), stream);
    hipMemsetAsync(cnt, 0, (size_t)(2 * BATCH * NS) * sizeof(float), stream);

    scatter_kernel<<<BATCH * NQ, DIMC, 0, stream>>>(xsrc, loc, csrc, feat, cnt, confsum);
    featfin_kernel<<<BATCH * NS, DIMC, 0, stream>>>(cnt, confsum, feat, conf);
    rowgemm16_kernel<true ><<<BATCH * NS / 16, DIMC, 0, stream>>>(feat, Wsr, bsr, xs);
    ln_kernel<<<BATCH * NS, DIMC, 0, stream>>>(xs, lng, lnb);
    rowgemm16_kernel<false><<<BATCH * NS / 16, DIMC, 0, stream>>>(xs, Wk, nullptr, kbuf);
    rowgemm16_kernel<false><<<BATCH * NS / 16, DIMC, 0, stream>>>(xs, Wv, nullptr, vbuf);
    rowgemm16_kernel<false><<<BATCH * NQ / 16, DIMC, 0, stream>>>(x, Wq, nullptr, qbuf);
    ksplit_kernel<<<MS / 2 / 256, 256, 0, stream>>>(kbuf, khi, klo);
    vtrans_kernel<<<BATCH * (NS / 32), 256, 0, stream>>>(vbuf, vthi, vtlo);
    attn_mfma_kernel<<<BATCH * NHEADS * (NQ / 128), 256, 0, stream>>>(
        qbuf, khi, klo, vthi, vtlo, conf, abuf);
    rowgemm16_kernel<true ><<<BATCH * NQ / 16, DIMC, 0, stream>>>(abuf, Wp, bp, outp);
}

// Round 3
// 331.662 us; speedup vs baseline: 1.8996x; 1.2485x over previous
//
#include <hip/hip_runtime.h>
#include <math.h>

#define DIMC   256
#define NQ     4096
#define BATCH  4
#define NS     1024    // (H/SR)*(W/SR) = 32*32
#define WG     32
#define HG     32
#define NHEADS 8
#define HDIM   32
#define SCALE_ATTN 0.17677669529663687f  // 32^-0.5

typedef __attribute__((ext_vector_type(8))) __bf16 bf16x8;
typedef __attribute__((ext_vector_type(4))) float  f32x4;

#define MFMA16(A, B, C) __builtin_amdgcn_mfma_f32_16x16x32_bf16((A), (B), (C), 0, 0, 0)

static __device__ __forceinline__ unsigned short bf16_hi(float v) {
    return __builtin_bit_cast(unsigned short, (__bf16)v);
}

// ---------------- scatter: token2map segment-sum ----------------
__global__ __launch_bounds__(DIMC) void scatter_kernel(
    const float* __restrict__ xsrc, const float* __restrict__ loc,
    const float* __restrict__ csrc, float* __restrict__ feat,
    float* __restrict__ cnt, float* __restrict__ confsum)
{
    int token = blockIdx.x;          // B*NQ tokens
    int b = token >> 12;             // NQ = 4096
    int c = threadIdx.x;
    float lx = loc[token * 2 + 0];
    float ly = loc[token * 2 + 1];
    lx = fminf(fmaxf(lx, 0.f), 1.f) * (float)(WG - 1);
    ly = fminf(fmaxf(ly, 0.f), 1.f) * (float)(HG - 1);
    int ix = (int)rintf(lx);         // round-half-even, matches jnp.round
    int iy = (int)rintf(ly);
    int cell = b * NS + iy * WG + ix;
    atomicAdd(&feat[cell * DIMC + c], xsrc[token * DIMC + c]);
    if (c == 0) {
        atomicAdd(&cnt[cell], 1.f);
        atomicAdd(&confsum[cell], csrc[token]);
    }
}

// ---------------- finalize: feat /= (cnt+eps), mask; conf map ----------------
__global__ __launch_bounds__(DIMC) void featfin_kernel(
    const float* __restrict__ cnt, const float* __restrict__ confsum,
    float* __restrict__ feat, float* __restrict__ conf)
{
    int m = blockIdx.x;              // B*NS cells
    int c = threadIdx.x;
    float cv = cnt[m];
    float inv = (cv > 0.f) ? 1.f / (cv + 1e-6f) : 0.f;
    feat[m * DIMC + c] *= inv;
    if (c == 0) conf[m] = confsum[m] * inv;
}

// ---------------- weight split: 5x fp32[256][256] -> bf16 hi/lo ----------------
__global__ __launch_bounds__(256) void wsplit_kernel(
    const float* __restrict__ W0, const float* __restrict__ W1,
    const float* __restrict__ W2, const float* __restrict__ W3,
    const float* __restrict__ W4,
    unsigned short* __restrict__ H0, unsigned short* __restrict__ L0,
    unsigned short* __restrict__ H1, unsigned short* __restrict__ L1,
    unsigned short* __restrict__ H2, unsigned short* __restrict__ L2,
    unsigned short* __restrict__ H3, unsigned short* __restrict__ L3,
    unsigned short* __restrict__ H4, unsigned short* __restrict__ L4)
{
    const float* W; unsigned short *H, *L;
    switch (blockIdx.y) {
        case 0: W = W0; H = H0; L = L0; break;
        case 1: W = W1; H = H1; L = L1; break;
        case 2: W = W2; H = H2; L = L2; break;
        case 3: W = W3; H = H3; L = L3; break;
        default: W = W4; H = H4; L = L4; break;
    }
    int i = (blockIdx.x * 256 + threadIdx.x) * 4;   // grid.x = 64 -> 65536 elems
    float4 v = *(const float4*)(W + i);
    float vv[4] = {v.x, v.y, v.z, v.w};
    ushort4 h, l;
    unsigned short* hp = &h.x; unsigned short* lp = &l.x;
    #pragma unroll
    for (int j = 0; j < 4; j++) {
        __bf16 hb = (__bf16)vv[j];
        hp[j] = __builtin_bit_cast(unsigned short, hb);
        lp[j] = bf16_hi(vv[j] - (float)hb);
    }
    *(ushort4*)(H + i) = h;
    *(ushort4*)(L + i) = l;
}

// ---------------- MFMA GEMM: C[M][256] = A[M][256] @ W^T (+bias) ----------------
// W given row-major [n][k] == B-operand order directly. bf16x2 split: 3 products.
// Block: 64 rows x 128 cols, 4 waves (wave = 16 rows x 128 cols = 8 col-frags).
// grid = (M/64, 2). EPI: 0=f32 row-major, 1=bf16 hi/lo row-major (K), 2=bf16 hi/lo
// transposed (V): out[(b*256+c)*1024 + key].
template <int EPI, bool HASBIAS>
__global__ __launch_bounds__(256) void mfma_gemm_kernel(
    const float* __restrict__ A,
    const unsigned short* __restrict__ Whi, const unsigned short* __restrict__ Wlo,
    const float* __restrict__ bias, float* __restrict__ outF,
    unsigned short* __restrict__ outHi, unsigned short* __restrict__ outLo)
{
    int r0 = blockIdx.x * 64;
    int c0 = blockIdx.y * 128;
    int wave = threadIdx.x >> 6;
    int lane = threadIdx.x & 63;
    int s = lane & 15, g = lane >> 4;

    int arow = r0 + wave * 16 + s;              // A-frag row for this lane
    const float* ap = A + (size_t)arow * DIMC + 8 * g;

    f32x4 acc[8];
    #pragma unroll
    for (int cf = 0; cf < 8; cf++) {
        float bv = HASBIAS ? bias[c0 + cf * 16 + s] : 0.f;
        acc[cf] = (f32x4){bv, bv, bv, bv};
    }

    #pragma unroll
    for (int kk = 0; kk < 8; kk++) {
        float4 a0 = *(const float4*)(ap + kk * 32);
        float4 a1 = *(const float4*)(ap + kk * 32 + 4);
        float av[8] = {a0.x, a0.y, a0.z, a0.w, a1.x, a1.y, a1.z, a1.w};
        bf16x8 ah, al;
        #pragma unroll
        for (int j = 0; j < 8; j++) {
            __bf16 hb = (__bf16)av[j];
            ah[j] = hb;
            al[j] = (__bf16)(av[j] - (float)hb);
        }
        #pragma unroll
        for (int cf = 0; cf < 8; cf++) {
            size_t woff = (size_t)(c0 + cf * 16 + s) * DIMC + kk * 32 + 8 * g;
            bf16x8 bh = *(const bf16x8*)(Whi + woff);
            bf16x8 bl = *(const bf16x8*)(Wlo + woff);
            acc[cf] = MFMA16(ah, bh, acc[cf]);
            acc[cf] = MFMA16(al, bh, acc[cf]);
            acc[cf] = MFMA16(ah, bl, acc[cf]);
        }
    }

    int rbase = r0 + wave * 16 + 4 * g;         // output rows rbase..rbase+3
    if (EPI == 0) {
        #pragma unroll
        for (int cf = 0; cf < 8; cf++) {
            int c = c0 + cf * 16 + s;
            #pragma unroll
            for (int r = 0; r < 4; r++)
                outF[(size_t)(rbase + r) * DIMC + c] = acc[cf][r];
        }
    } else if (EPI == 1) {
        #pragma unroll
        for (int cf = 0; cf < 8; cf++) {
            int c = c0 + cf * 16 + s;
            #pragma unroll
            for (int r = 0; r < 4; r++) {
                float v = acc[cf][r];
                __bf16 hb = (__bf16)v;
                size_t idx = (size_t)(rbase + r) * DIMC + c;
                outHi[idx] = __builtin_bit_cast(unsigned short, hb);
                outLo[idx] = bf16_hi(v - (float)hb);
            }
        }
    } else {
        int b = rbase >> 10;                    // 64-row blocks never cross batch
        int key0 = rbase & 1023;
        #pragma unroll
        for (int cf = 0; cf < 8; cf++) {
            int c = c0 + cf * 16 + s;
            ushort4 h, l;
            unsigned short* hp = &h.x; unsigned short* lp = &l.x;
            #pragma unroll
            for (int r = 0; r < 4; r++) {
                float v = acc[cf][r];
                __bf16 hb = (__bf16)v;
                hp[r] = __builtin_bit_cast(unsigned short, hb);
                lp[r] = bf16_hi(v - (float)hb);
            }
            size_t off = ((size_t)(b * DIMC + c)) * NS + key0;
            *(ushort4*)(outHi + off) = h;
            *(ushort4*)(outLo + off) = l;
        }
    }
}

// ---------------- layernorm in place over last dim ----------------
__global__ __launch_bounds__(DIMC) void ln_kernel(
    float* __restrict__ xs, const float* __restrict__ g, const float* __restrict__ b)
{
    int m = blockIdx.x;
    int c = threadIdx.x;
    float v = xs[(size_t)m * DIMC + c];
    float s = v, q = v * v;
    #pragma unroll
    for (int off = 32; off > 0; off >>= 1) {
        s += __shfl_xor(s, off);
        q += __shfl_xor(q, off);
    }
    __shared__ float sh1[4], sh2[4];
    int wid = c >> 6, lane = c & 63;
    if (lane == 0) { sh1[wid] = s; sh2[wid] = q; }
    __syncthreads();
    s = sh1[0] + sh1[1] + sh1[2] + sh1[3];
    q = sh2[0] + sh2[1] + sh2[2] + sh2[3];
    float mu  = s * (1.f / DIMC);
    float var = q * (1.f / DIMC) - mu * mu;
    xs[(size_t)m * DIMC + c] = (v - mu) * rsqrtf(var + 1e-5f) * g[c] + b[c];
}

// ---------------- MFMA flash attention (bf16x2 split, swapped-operand) ----------------
__global__ __launch_bounds__(256) void attn_mfma_kernel(
    const float* __restrict__ qbuf,
    const unsigned short* __restrict__ khi, const unsigned short* __restrict__ klo,
    const unsigned short* __restrict__ vthi, const unsigned short* __restrict__ vtlo,
    const float* __restrict__ conf, float* __restrict__ abuf)
{
    int blk  = blockIdx.x;            // B*H*(NQ/128) = 1024
    int qt   = blk & 31;              // NQ/128 = 32
    int bh   = blk >> 5;
    int hh   = bh & (NHEADS - 1);
    int b    = bh >> 3;
    int wave = threadIdx.x >> 6;
    int lane = threadIdx.x & 63;
    int s = lane & 15, g = lane >> 4;
    int q0 = qt * 128 + wave * 32;

    bf16x8 qh[2], ql[2];
    #pragma unroll
    for (int qf = 0; qf < 2; qf++) {
        const float* qp = qbuf + ((size_t)(b * NQ + q0 + qf * 16 + s)) * DIMC + hh * HDIM + 8 * g;
        float4 a = *(const float4*)qp;
        float4 c = *(const float4*)(qp + 4);
        float qv[8] = {a.x, a.y, a.z, a.w, c.x, c.y, c.z, c.w};
        #pragma unroll
        for (int j = 0; j < 8; j++) {
            __bf16 hi = (__bf16)qv[j];
            qh[qf][j] = hi;
            ql[qf][j] = (__bf16)(qv[j] - (float)hi);
        }
    }

    f32x4 oacc[2][2];
    #pragma unroll
    for (int qf = 0; qf < 2; qf++)
        #pragma unroll
        for (int m = 0; m < 2; m++)
            oacc[qf][m] = (f32x4){0.f, 0.f, 0.f, 0.f};
    float mrun[2] = {-INFINITY, -INFINITY};
    float lrun[2] = {0.f, 0.f};

    const unsigned short* khb = khi + ((size_t)(b * NS)) * DIMC + hh * HDIM + 8 * g;
    const unsigned short* klb = klo + ((size_t)(b * NS)) * DIMC + hh * HDIM + 8 * g;
    const unsigned short* vhb = vthi + ((size_t)(bh * HDIM)) * NS + 8 * g;
    const unsigned short* vlb = vtlo + ((size_t)(bh * HDIM)) * NS + 8 * g;
    const float* cfb = conf + b * NS + 4 * g;

    int addr0 = (s + ((g & 1) << 5)) << 2;   // src lane s + 32*(g&1), bytes
    int addr1 = addr0 + 64;                  // +16 lanes
    bool hiHalf = (g >= 2);                  // source frag = g>>1

    for (int k0 = 0; k0 < NS; k0 += 32) {
        bf16x8 kh[2], kl[2];
        #pragma unroll
        for (int f = 0; f < 2; f++) {
            size_t roff = ((size_t)(k0 + 16 * f + s)) * DIMC;
            kh[f] = *(const bf16x8*)(khb + roff);
            kl[f] = *(const bf16x8*)(klb + roff);
        }
        bf16x8 vh[2], vl[2];
        #pragma unroll
        for (int m = 0; m < 2; m++) {
            size_t off = ((size_t)(16 * m + s)) * NS + k0;
            vh[m] = *(const bf16x8*)(vhb + off);
            vl[m] = *(const bf16x8*)(vlb + off);
        }
        float cv[2][4];
        #pragma unroll
        for (int f = 0; f < 2; f++)
            #pragma unroll
            for (int r = 0; r < 4; r++)
                cv[f][r] = cfb[k0 + 16 * f + r];

        #pragma unroll
        for (int qf = 0; qf < 2; qf++) {
            f32x4 sa[2];
            #pragma unroll
            for (int f = 0; f < 2; f++) {
                f32x4 z = (f32x4){0.f, 0.f, 0.f, 0.f};
                z = MFMA16(kh[f], qh[qf], z);
                z = MFMA16(kh[f], ql[qf], z);
                z = MFMA16(kl[f], qh[qf], z);
                sa[f] = z;
            }
            float sc[2][4], mc = -INFINITY;
            #pragma unroll
            for (int f = 0; f < 2; f++)
                #pragma unroll
                for (int r = 0; r < 4; r++) {
                    sc[f][r] = sa[f][r] * SCALE_ATTN + cv[f][r];
                    mc = fmaxf(mc, sc[f][r]);
                }
            mc = fmaxf(mc, __shfl_xor(mc, 16));
            mc = fmaxf(mc, __shfl_xor(mc, 32));
            float mnew = fmaxf(mrun[qf], mc);
            float corr = __expf(mrun[qf] - mnew);   // exp(-inf)=0 first chunk
            mrun[qf] = mnew;
            float p[2][4], ls = 0.f;
            #pragma unroll
            for (int f = 0; f < 2; f++)
                #pragma unroll
                for (int r = 0; r < 4; r++) {
                    p[f][r] = __expf(sc[f][r] - mnew);
                    ls += p[f][r];
                }
            ls += __shfl_xor(ls, 16);
            ls += __shfl_xor(ls, 32);
            lrun[qf] = lrun[qf] * corr + ls;
            #pragma unroll
            for (int m = 0; m < 2; m++)
                #pragma unroll
                for (int r = 0; r < 4; r++)
                    oacc[qf][m][r] *= corr;

            unsigned whiw[2][2], wlow[2][2];
            #pragma unroll
            for (int f = 0; f < 2; f++)
                #pragma unroll
                for (int r2 = 0; r2 < 2; r2++) {
                    float p0 = p[f][2 * r2], p1 = p[f][2 * r2 + 1];
                    __bf16 h0 = (__bf16)p0, h1 = (__bf16)p1;
                    __bf16 l0 = (__bf16)(p0 - (float)h0), l1 = (__bf16)(p1 - (float)h1);
                    whiw[f][r2] = (unsigned)__builtin_bit_cast(unsigned short, h0)
                               | ((unsigned)__builtin_bit_cast(unsigned short, h1) << 16);
                    wlow[f][r2] = (unsigned)__builtin_bit_cast(unsigned short, l0)
                               | ((unsigned)__builtin_bit_cast(unsigned short, l1) << 16);
                }
            unsigned bwh[4], bwl[4];
            {
                int a0h = __builtin_amdgcn_ds_bpermute(addr0, (int)whiw[0][0]);
                int a0h1 = __builtin_amdgcn_ds_bpermute(addr0, (int)whiw[1][0]);
                bwh[0] = (unsigned)(hiHalf ? a0h1 : a0h);
                int a1h = __builtin_amdgcn_ds_bpermute(addr0, (int)whiw[0][1]);
                int a1h1 = __builtin_amdgcn_ds_bpermute(addr0, (int)whiw[1][1]);
                bwh[1] = (unsigned)(hiHalf ? a1h1 : a1h);
                int a2h = __builtin_amdgcn_ds_bpermute(addr1, (int)whiw[0][0]);
                int a2h1 = __builtin_amdgcn_ds_bpermute(addr1, (int)whiw[1][0]);
                bwh[2] = (unsigned)(hiHalf ? a2h1 : a2h);
                int a3h = __builtin_amdgcn_ds_bpermute(addr1, (int)whiw[0][1]);
                int a3h1 = __builtin_amdgcn_ds_bpermute(addr1, (int)whiw[1][1]);
                bwh[3] = (unsigned)(hiHalf ? a3h1 : a3h);
                int b0 = __builtin_amdgcn_ds_bpermute(addr0, (int)wlow[0][0]);
                int b0h = __builtin_amdgcn_ds_bpermute(addr0, (int)wlow[1][0]);
                bwl[0] = (unsigned)(hiHalf ? b0h : b0);
                int b1 = __builtin_amdgcn_ds_bpermute(addr0, (int)wlow[0][1]);
                int b1h = __builtin_amdgcn_ds_bpermute(addr0, (int)wlow[1][1]);
                bwl[1] = (unsigned)(hiHalf ? b1h : b1);
                int b2 = __builtin_amdgcn_ds_bpermute(addr1, (int)wlow[0][0]);
                int b2h = __builtin_amdgcn_ds_bpermute(addr1, (int)wlow[1][0]);
                bwl[2] = (unsigned)(hiHalf ? b2h : b2);
                int b3 = __builtin_amdgcn_ds_bpermute(addr1, (int)wlow[0][1]);
                int b3h = __builtin_amdgcn_ds_bpermute(addr1, (int)wlow[1][1]);
                bwl[3] = (unsigned)(hiHalf ? b3h : b3);
            }
            union { unsigned u[4]; bf16x8 v; } Bh, Bl;
            #pragma unroll
            for (int j = 0; j < 4; j++) { Bh.u[j] = bwh[j]; Bl.u[j] = bwl[j]; }
            #pragma unroll
            for (int m = 0; m < 2; m++) {
                oacc[qf][m] = MFMA16(vh[m], Bh.v, oacc[qf][m]);
                oacc[qf][m] = MFMA16(vl[m], Bh.v, oacc[qf][m]);
                oacc[qf][m] = MFMA16(vh[m], Bl.v, oacc[qf][m]);
            }
        } // qf
    } // chunk

    #pragma unroll
    for (int qf = 0; qf < 2; qf++) {
        float invl = 1.f / lrun[qf];
        float* orow = abuf + ((size_t)(b * NQ + q0 + qf * 16 + s)) * DIMC + hh * HDIM;
        #pragma unroll
        for (int m = 0; m < 2; m++) {
            float4 o;
            o.x = oacc[qf][m][0] * invl;
            o.y = oacc[qf][m][1] * invl;
            o.z = oacc[qf][m][2] * invl;
            o.w = oacc[qf][m][3] * invl;
            *(float4*)(orow + 16 * m + 4 * g) = o;
        }
    }
}

extern "C" void kernel_launch(void* const* d_in, const int* in_sizes, int n_in,
                              void* d_out, int out_size, void* d_ws, size_t ws_size,
                              hipStream_t stream)
{
    (void)in_sizes; (void)n_in; (void)out_size; (void)ws_size;
    const float* x    = (const float*)d_in[0];
    const float* xsrc = (const float*)d_in[1];
    const float* loc  = (const float*)d_in[2];
    const float* csrc = (const float*)d_in[3];
    const float* Wq   = (const float*)d_in[4];
    const float* Wk   = (const float*)d_in[5];
    const float* Wv   = (const float*)d_in[6];
    const float* Wsr  = (const float*)d_in[7];
    const float* bsr  = (const float*)d_in[8];
    const float* lng  = (const float*)d_in[9];
    const float* lnb  = (const float*)d_in[10];
    const float* Wp   = (const float*)d_in[11];
    const float* bp   = (const float*)d_in[12];
    // d_in[13]=H(64), d_in[14]=W(64): fixed by setup_inputs; h=w=32 hardcoded.

    const int MS = BATCH * NS * DIMC;     // 1,048,576
    const int MQ = BATCH * NQ * DIMC;     // 4,194,304
    const int WSZ = DIMC * DIMC;          // 65,536

    float* ws   = (float*)d_ws;
    float* abuf = ws;                     // 4M floats (16 MB)
    float* feat = ws;                     //   alias: dead before attn
    float* xs   = ws + MS;                //   alias: dead before attn
    float* qbuf = ws + (size_t)MQ;        // 4M floats
    float* cnt     = qbuf + MQ;           // 4096
    float* confsum = cnt + BATCH * NS;    // 4096
    float* conf    = confsum + BATCH * NS;// 4096
    unsigned short* us   = (unsigned short*)(conf + BATCH * NS);
    unsigned short* khi  = us;            // 1M ushorts each
    unsigned short* klo  = khi  + MS;
    unsigned short* vthi = klo  + MS;
    unsigned short* vtlo = vthi + MS;
    unsigned short* wsrh = vtlo + MS;     // 10 x 65536 ushorts
    unsigned short* wsrl = wsrh + WSZ;
    unsigned short* wkh  = wsrl + WSZ;
    unsigned short* wkl  = wkh  + WSZ;
    unsigned short* wvh  = wkl  + WSZ;
    unsigned short* wvl  = wvh  + WSZ;
    unsigned short* wqh  = wvl  + WSZ;
    unsigned short* wql  = wqh  + WSZ;
    unsigned short* wph  = wql  + WSZ;
    unsigned short* wpl  = wph  + WSZ;    // total ~41.3 MB
    float* outp = (float*)d_out;

    hipMemsetAsync(feat, 0, (size_t)MS * sizeof(float), stream);
    hipMemsetAsync(cnt, 0, (size_t)(2 * BATCH * NS) * sizeof(float), stream);

    wsplit_kernel<<<dim3(64, 5), 256, 0, stream>>>(
        Wsr, Wk, Wv, Wq, Wp,
        wsrh, wsrl, wkh, wkl, wvh, wvl, wqh, wql, wph, wpl);
    scatter_kernel<<<BATCH * NQ, DIMC, 0, stream>>>(xsrc, loc, csrc, feat, cnt, confsum);
    featfin_kernel<<<BATCH * NS, DIMC, 0, stream>>>(cnt, confsum, feat, conf);
    mfma_gemm_kernel<0, true ><<<dim3(BATCH * NS / 64, 2), 256, 0, stream>>>(
        feat, wsrh, wsrl, bsr, xs, nullptr, nullptr);
    ln_kernel<<<BATCH * NS, DIMC, 0, stream>>>(xs, lng, lnb);
    mfma_gemm_kernel<1, false><<<dim3(BATCH * NS / 64, 2), 256, 0, stream>>>(
        xs, wkh, wkl, nullptr, nullptr, khi, klo);
    mfma_gemm_kernel<2, false><<<dim3(BATCH * NS / 64, 2), 256, 0, stream>>>(
        xs, wvh, wvl, nullptr, nullptr, vthi, vtlo);
    mfma_gemm_kernel<0, false><<<dim3(BATCH * NQ / 64, 2), 256, 0, stream>>>(
        x, wqh, wql, nullptr, qbuf, nullptr, nullptr);
    attn_mfma_kernel<<<BATCH * NHEADS * (NQ / 128), 256, 0, stream>>>(
        qbuf, khi, klo, vthi, vtlo, conf, abuf);
    mfma_gemm_kernel<0, true ><<<dim3(BATCH * NQ / 64, 2), 256, 0, stream>>>(
        abuf, wph, wpl, bp, outp, nullptr, nullptr);
}

// Round 5
// 272.241 us; speedup vs baseline: 2.3142x; 1.2183x over previous
//
#include <hip/hip_runtime.h>
#include <math.h>

#define DIMC   256
#define NQ     4096
#define BATCH  4
#define NS     1024    // (H/SR)*(W/SR) = 32*32
#define WG     32
#define HG     32
#define NHEADS 8
#define HDIM   32
#define SCALE_ATTN 0.17677669529663687f  // 32^-0.5

typedef _Float16 f16;
typedef __attribute__((ext_vector_type(8))) __bf16    bf16x8;
typedef __attribute__((ext_vector_type(8))) _Float16  f16x8;
typedef __attribute__((ext_vector_type(4))) _Float16  f16x4;
typedef __attribute__((ext_vector_type(4))) float     f32x4;

#define MFMA16B(A, B, C) __builtin_amdgcn_mfma_f32_16x16x32_bf16((A), (B), (C), 0, 0, 0)
#define MFMA16F(A, B, C) __builtin_amdgcn_mfma_f32_16x16x32_f16((A), (B), (C), 0, 0, 0)

static __device__ __forceinline__ unsigned short bf16_hi(float v) {
    return __builtin_bit_cast(unsigned short, (__bf16)v);
}

// ---------------- scatter: token2map segment-sum ----------------
__global__ __launch_bounds__(DIMC) void scatter_kernel(
    const float* __restrict__ xsrc, const float* __restrict__ loc,
    const float* __restrict__ csrc, float* __restrict__ feat,
    float* __restrict__ cnt, float* __restrict__ confsum)
{
    int token = blockIdx.x;          // B*NQ tokens
    int b = token >> 12;             // NQ = 4096
    int c = threadIdx.x;
    float lx = loc[token * 2 + 0];
    float ly = loc[token * 2 + 1];
    lx = fminf(fmaxf(lx, 0.f), 1.f) * (float)(WG - 1);
    ly = fminf(fmaxf(ly, 0.f), 1.f) * (float)(HG - 1);
    int ix = (int)rintf(lx);         // round-half-even, matches jnp.round
    int iy = (int)rintf(ly);
    int cell = b * NS + iy * WG + ix;
    atomicAdd(&feat[cell * DIMC + c], xsrc[token * DIMC + c]);
    if (c == 0) {
        atomicAdd(&cnt[cell], 1.f);
        atomicAdd(&confsum[cell], csrc[token]);
    }
}

// ---------------- finalize: feat /= (cnt+eps), mask; conf map ----------------
__global__ __launch_bounds__(DIMC) void featfin_kernel(
    const float* __restrict__ cnt, const float* __restrict__ confsum,
    float* __restrict__ feat, float* __restrict__ conf)
{
    int m = blockIdx.x;              // B*NS cells
    int c = threadIdx.x;
    float cv = cnt[m];
    float inv = (cv > 0.f) ? 1.f / (cv + 1e-6f) : 0.f;
    feat[m * DIMC + c] *= inv;
    if (c == 0) conf[m] = confsum[m] * inv;
}

// ---------------- weight split: 5x fp32[256][256] -> bf16 hi/lo ----------------
__global__ __launch_bounds__(256) void wsplit_kernel(
    const float* __restrict__ W0, const float* __restrict__ W1,
    const float* __restrict__ W2, const float* __restrict__ W3,
    const float* __restrict__ W4,
    unsigned short* __restrict__ H0, unsigned short* __restrict__ L0,
    unsigned short* __restrict__ H1, unsigned short* __restrict__ L1,
    unsigned short* __restrict__ H2, unsigned short* __restrict__ L2,
    unsigned short* __restrict__ H3, unsigned short* __restrict__ L3,
    unsigned short* __restrict__ H4, unsigned short* __restrict__ L4)
{
    const float* W; unsigned short *H, *L;
    switch (blockIdx.y) {
        case 0: W = W0; H = H0; L = L0; break;
        case 1: W = W1; H = H1; L = L1; break;
        case 2: W = W2; H = H2; L = L2; break;
        case 3: W = W3; H = H3; L = L3; break;
        default: W = W4; H = H4; L = L4; break;
    }
    int i = (blockIdx.x * 256 + threadIdx.x) * 4;   // grid.x = 64 -> 65536 elems
    float4 v = *(const float4*)(W + i);
    float vv[4] = {v.x, v.y, v.z, v.w};
    ushort4 h, l;
    unsigned short* hp = &h.x; unsigned short* lp = &l.x;
    #pragma unroll
    for (int j = 0; j < 4; j++) {
        __bf16 hb = (__bf16)vv[j];
        hp[j] = __builtin_bit_cast(unsigned short, hb);
        lp[j] = bf16_hi(vv[j] - (float)hb);
    }
    *(ushort4*)(H + i) = h;
    *(ushort4*)(L + i) = l;
}

// ---------------- MFMA GEMM: C[M][256] = A[M][256] @ W^T (+bias) ----------------
// bf16x2-split A x W (3 products). Block: 64 rows x 128 cols, 4 waves.
// EPI: 0 = f32 row-major; 1 = fp16 row-major (K, Q); 2 = fp16 hi/lo transposed (V).
template <int EPI, bool HASBIAS>
__global__ __launch_bounds__(256) void mfma_gemm_kernel(
    const float* __restrict__ A,
    const unsigned short* __restrict__ Whi, const unsigned short* __restrict__ Wlo,
    const float* __restrict__ bias, float* __restrict__ outF,
    f16* __restrict__ o16a, f16* __restrict__ o16b)
{
    int r0 = blockIdx.x * 64;
    int c0 = blockIdx.y * 128;
    int wave = threadIdx.x >> 6;
    int lane = threadIdx.x & 63;
    int s = lane & 15, g = lane >> 4;

    int arow = r0 + wave * 16 + s;              // A-frag row for this lane
    const float* ap = A + (size_t)arow * DIMC + 8 * g;

    f32x4 acc[8];
    #pragma unroll
    for (int cf = 0; cf < 8; cf++) {
        float bv = HASBIAS ? bias[c0 + cf * 16 + s] : 0.f;
        acc[cf] = (f32x4){bv, bv, bv, bv};
    }

    #pragma unroll
    for (int kk = 0; kk < 8; kk++) {
        float4 a0 = *(const float4*)(ap + kk * 32);
        float4 a1 = *(const float4*)(ap + kk * 32 + 4);
        float av[8] = {a0.x, a0.y, a0.z, a0.w, a1.x, a1.y, a1.z, a1.w};
        bf16x8 ah, al;
        #pragma unroll
        for (int j = 0; j < 8; j++) {
            __bf16 hb = (__bf16)av[j];
            ah[j] = hb;
            al[j] = (__bf16)(av[j] - (float)hb);
        }
        #pragma unroll
        for (int cf = 0; cf < 8; cf++) {
            size_t woff = (size_t)(c0 + cf * 16 + s) * DIMC + kk * 32 + 8 * g;
            bf16x8 bh = *(const bf16x8*)(Whi + woff);
            bf16x8 bl = *(const bf16x8*)(Wlo + woff);
            acc[cf] = MFMA16B(ah, bh, acc[cf]);
            acc[cf] = MFMA16B(al, bh, acc[cf]);
            acc[cf] = MFMA16B(ah, bl, acc[cf]);
        }
    }

    int rbase = r0 + wave * 16 + 4 * g;         // output rows rbase..rbase+3
    if (EPI == 0) {
        #pragma unroll
        for (int cf = 0; cf < 8; cf++) {
            int c = c0 + cf * 16 + s;
            #pragma unroll
            for (int r = 0; r < 4; r++)
                outF[(size_t)(rbase + r) * DIMC + c] = acc[cf][r];
        }
    } else if (EPI == 1) {
        #pragma unroll
        for (int cf = 0; cf < 8; cf++) {
            int c = c0 + cf * 16 + s;
            #pragma unroll
            for (int r = 0; r < 4; r++)
                o16a[(size_t)(rbase + r) * DIMC + c] = (f16)acc[cf][r];
        }
    } else {
        int b = rbase >> 10;                    // 64-row blocks never cross batch
        int key0 = rbase & 1023;
        #pragma unroll
        for (int cf = 0; cf < 8; cf++) {
            int c = c0 + cf * 16 + s;
            f16x4 h, l;
            #pragma unroll
            for (int r = 0; r < 4; r++) {
                float v = acc[cf][r];
                f16 hb = (f16)v;
                h[r] = hb;
                l[r] = (f16)(v - (float)hb);
            }
            size_t off = ((size_t)(b * DIMC + c)) * NS + key0;
            *(f16x4*)(o16a + off) = h;
            *(f16x4*)(o16b + off) = l;
        }
    }
}

// ---------------- layernorm in place over last dim ----------------
__global__ __launch_bounds__(DIMC) void ln_kernel(
    float* __restrict__ xs, const float* __restrict__ g, const float* __restrict__ b)
{
    int m = blockIdx.x;
    int c = threadIdx.x;
    float v = xs[(size_t)m * DIMC + c];
    float s = v, q = v * v;
    #pragma unroll
    for (int off = 32; off > 0; off >>= 1) {
        s += __shfl_xor(s, off);
        q += __shfl_xor(q, off);
    }
    __shared__ float sh1[4], sh2[4];
    int wid = c >> 6, lane = c & 63;
    if (lane == 0) { sh1[wid] = s; sh2[wid] = q; }
    __syncthreads();
    s = sh1[0] + sh1[1] + sh1[2] + sh1[3];
    q = sh2[0] + sh2[1] + sh2[2] + sh2[3];
    float mu  = s * (1.f / DIMC);
    float var = q * (1.f / DIMC) - mu * mu;
    xs[(size_t)m * DIMC + c] = (v - mu) * rsqrtf(var + 1e-5f) * g[c] + b[c];
}

// ---------------- MFMA flash attention (fp16, swapped-operand) ----------------
// Q,K fp16 single (softmax-cancelling noise); V fp16 hi+lo (2 PV products);
// P fp16 single via cvt_pkrtz; exact skip-rescale.
__global__ __launch_bounds__(256) void attn_mfma_kernel(
    const f16* __restrict__ qbuf, const f16* __restrict__ kbuf,
    const f16* __restrict__ vthi, const f16* __restrict__ vtlo,
    const float* __restrict__ conf, float* __restrict__ abuf)
{
    int blk  = blockIdx.x;            // B*H*(NQ/128) = 1024
    int qt   = blk & 31;              // NQ/128 = 32
    int bh   = blk >> 5;
    int hh   = bh & (NHEADS - 1);
    int b    = bh >> 3;
    int wave = threadIdx.x >> 6;
    int lane = threadIdx.x & 63;
    int s = lane & 15, g = lane >> 4;
    int q0 = qt * 128 + wave * 32;

    // Q fragments (B-operand for S^T): lane holds Q[q0+qf*16+s][d=8g+j]
    f16x8 qh[2];
    #pragma unroll
    for (int qf = 0; qf < 2; qf++)
        qh[qf] = *(const f16x8*)(qbuf +
            ((size_t)(b * NQ + q0 + qf * 16 + s)) * DIMC + hh * HDIM + 8 * g);

    f32x4 oacc[2][2];
    #pragma unroll
    for (int qf = 0; qf < 2; qf++)
        #pragma unroll
        for (int m = 0; m < 2; m++)
            oacc[qf][m] = (f32x4){0.f, 0.f, 0.f, 0.f};
    float mrun[2] = {-INFINITY, -INFINITY};
    float lrun[2] = {0.f, 0.f};

    const f16* khb = kbuf + ((size_t)(b * NS)) * DIMC + hh * HDIM + 8 * g;
    const f16* vhb = vthi + ((size_t)(bh * HDIM)) * NS + 8 * g;
    const f16* vlb = vtlo + ((size_t)(bh * HDIM)) * NS + 8 * g;
    const float* cfb = conf + b * NS + 4 * g;

    int addr0 = (s + ((g & 1) << 5)) << 2;   // src lane s + 32*(g&1), bytes
    int addr1 = addr0 + 64;                  // +16 lanes
    bool hiHalf = (g >= 2);                  // source frag = g>>1

    for (int k0 = 0; k0 < NS; k0 += 32) {
        // K fragments (A-operand): lane holds K[k0+16f+s][d=8g+j]
        f16x8 kh[2];
        #pragma unroll
        for (int f = 0; f < 2; f++)
            kh[f] = *(const f16x8*)(khb + ((size_t)(k0 + 16 * f + s)) * DIMC);
        // V^T fragments (A-operand for PV): lane holds Vt[16m+s][k0+8g+j]
        f16x8 vh[2], vl[2];
        #pragma unroll
        for (int m = 0; m < 2; m++) {
            size_t off = ((size_t)(16 * m + s)) * NS + k0;
            vh[m] = *(const f16x8*)(vhb + off);
            vl[m] = *(const f16x8*)(vlb + off);
        }
        float cv[2][4];
        #pragma unroll
        for (int f = 0; f < 2; f++)
            #pragma unroll
            for (int r = 0; r < 4; r++)
                cv[f][r] = cfb[k0 + 16 * f + r];

        #pragma unroll
        for (int qf = 0; qf < 2; qf++) {
            // S^T = K * Q^T (single fp16 product)
            f32x4 sa[2];
            #pragma unroll
            for (int f = 0; f < 2; f++) {
                f32x4 z = (f32x4){0.f, 0.f, 0.f, 0.f};
                sa[f] = MFMA16F(kh[f], qh[qf], z);
            }
            float sc[2][4], mc = -INFINITY;
            #pragma unroll
            for (int f = 0; f < 2; f++)
                #pragma unroll
                for (int r = 0; r < 4; r++) {
                    sc[f][r] = sa[f][r] * SCALE_ATTN + cv[f][r];
                    mc = fmaxf(mc, sc[f][r]);
                }
            mc = fmaxf(mc, __shfl_xor(mc, 16));
            mc = fmaxf(mc, __shfl_xor(mc, 32));
            if (__any(mc > mrun[qf])) {          // exact skip: corr==1 otherwise
                float mnew = fmaxf(mrun[qf], mc);
                float corr = __expf(mrun[qf] - mnew);  // exp(-inf)=0 first chunk
                mrun[qf] = mnew;
                lrun[qf] *= corr;
                #pragma unroll
                for (int m = 0; m < 2; m++)
                    #pragma unroll
                    for (int r = 0; r < 4; r++)
                        oacc[qf][m][r] *= corr;
            }
            float p[2][4], ls = 0.f;
            #pragma unroll
            for (int f = 0; f < 2; f++)
                #pragma unroll
                for (int r = 0; r < 4; r++) {
                    p[f][r] = __expf(sc[f][r] - mrun[qf]);
                    ls += p[f][r];
                }
            ls += __shfl_xor(ls, 16);
            ls += __shfl_xor(ls, 32);
            lrun[qf] += ls;

            // P -> fp16 packed words: w[f][r2] = keys {16f+4g+2r2, +1}
            unsigned w[2][2];
            #pragma unroll
            for (int f = 0; f < 2; f++)
                #pragma unroll
                for (int r2 = 0; r2 < 2; r2++)
                    w[f][r2] = __builtin_bit_cast(unsigned,
                        __builtin_amdgcn_cvt_pkrtz(p[f][2 * r2], p[f][2 * r2 + 1]));
            // gather to PV B-operand: lane gets P^T[key=8g+2j,2j+1][q=s]
            unsigned bw[4];
            {
                int a0 = __builtin_amdgcn_ds_bpermute(addr0, (int)w[0][0]);
                int a0h = __builtin_amdgcn_ds_bpermute(addr0, (int)w[1][0]);
                bw[0] = (unsigned)(hiHalf ? a0h : a0);
                int a1 = __builtin_amdgcn_ds_bpermute(addr0, (int)w[0][1]);
                int a1h = __builtin_amdgcn_ds_bpermute(addr0, (int)w[1][1]);
                bw[1] = (unsigned)(hiHalf ? a1h : a1);
                int a2 = __builtin_amdgcn_ds_bpermute(addr1, (int)w[0][0]);
                int a2h = __builtin_amdgcn_ds_bpermute(addr1, (int)w[1][0]);
                bw[2] = (unsigned)(hiHalf ? a2h : a2);
                int a3 = __builtin_amdgcn_ds_bpermute(addr1, (int)w[0][1]);
                int a3h = __builtin_amdgcn_ds_bpermute(addr1, (int)w[1][1]);
                bw[3] = (unsigned)(hiHalf ? a3h : a3);
            }
            union { unsigned u[4]; f16x8 v; } Bv;
            #pragma unroll
            for (int j = 0; j < 4; j++) Bv.u[j] = bw[j];
            // O^T += V^T * P^T (Vhi + Vlo products)
            #pragma unroll
            for (int m = 0; m < 2; m++) {
                oacc[qf][m] = MFMA16F(vh[m], Bv.v, oacc[qf][m]);
                oacc[qf][m] = MFMA16F(vl[m], Bv.v, oacc[qf][m]);
            }
        } // qf
    } // chunk

    // epilogue: oacc[qf][m][r] = O^T[d=16m+4g+r][q=q0+16qf+s]
    #pragma unroll
    for (int qf = 0; qf < 2; qf++) {
        float invl = 1.f / lrun[qf];
        float* orow = abuf + ((size_t)(b * NQ + q0 + qf * 16 + s)) * DIMC + hh * HDIM;
        #pragma unroll
        for (int m = 0; m < 2; m++) {
            float4 o;
            o.x = oacc[qf][m][0] * invl;
            o.y = oacc[qf][m][1] * invl;
            o.z = oacc[qf][m][2] * invl;
            o.w = oacc[qf][m][3] * invl;
            *(float4*)(orow + 16 * m + 4 * g) = o;
        }
    }
}

extern "C" void kernel_launch(void* const* d_in, const int* in_sizes, int n_in,
                              void* d_out, int out_size, void* d_ws, size_t ws_size,
                              hipStream_t stream)
{
    (void)in_sizes; (void)n_in; (void)out_size; (void)ws_size;
    const float* x    = (const float*)d_in[0];
    const float* xsrc = (const float*)d_in[1];
    const float* loc  = (const float*)d_in[2];
    const float* csrc = (const float*)d_in[3];
    const float* Wq   = (const float*)d_in[4];
    const float* Wk   = (const float*)d_in[5];
    const float* Wv   = (const float*)d_in[6];
    const float* Wsr  = (const float*)d_in[7];
    const float* bsr  = (const float*)d_in[8];
    const float* lng  = (const float*)d_in[9];
    const float* lnb  = (const float*)d_in[10];
    const float* Wp   = (const float*)d_in[11];
    const float* bp   = (const float*)d_in[12];
    // d_in[13]=H(64), d_in[14]=W(64): fixed by setup_inputs; h=w=32 hardcoded.

    const int MS = BATCH * NS * DIMC;     // 1,048,576
    const int MQ = BATCH * NQ * DIMC;     // 4,194,304
    const int WSZ = DIMC * DIMC;          // 65,536

    float* ws   = (float*)d_ws;
    float* abuf = ws;                     // 4M floats (16 MB)
    float* feat = ws;                     //   alias: dead before attn
    float* xs   = ws + MS;                //   alias: dead before attn
    float* cnt     = ws + MQ;             // 4096
    float* confsum = cnt + BATCH * NS;    // 4096
    float* conf    = confsum + BATCH * NS;// 4096
    f16* q16    = (f16*)(conf + BATCH * NS);  // 4M f16
    f16* k16    = q16 + MQ;               // 1M f16
    f16* vthi16 = k16 + MS;               // 1M f16
    f16* vtlo16 = vthi16 + MS;            // 1M f16
    unsigned short* wsrh = (unsigned short*)(vtlo16 + MS);  // 10 x 65536 ushorts
    unsigned short* wsrl = wsrh + WSZ;
    unsigned short* wkh  = wsrl + WSZ;
    unsigned short* wkl  = wkh  + WSZ;
    unsigned short* wvh  = wkl  + WSZ;
    unsigned short* wvl  = wvh  + WSZ;
    unsigned short* wqh  = wvl  + WSZ;
    unsigned short* wql  = wqh  + WSZ;
    unsigned short* wph  = wql  + WSZ;
    unsigned short* wpl  = wph  + WSZ;    // total ~31.6 MB
    float* outp = (float*)d_out;

    hipMemsetAsync(feat, 0, (size_t)MS * sizeof(float), stream);
    hipMemsetAsync(cnt, 0, (size_t)(2 * BATCH * NS) * sizeof(float), stream);

    wsplit_kernel<<<dim3(64, 5), 256, 0, stream>>>(
        Wsr, Wk, Wv, Wq, Wp,
        wsrh, wsrl, wkh, wkl, wvh, wvl, wqh, wql, wph, wpl);
    scatter_kernel<<<BATCH * NQ, DIMC, 0, stream>>>(xsrc, loc, csrc, feat, cnt, confsum);
    featfin_kernel<<<BATCH * NS, DIMC, 0, stream>>>(cnt, confsum, feat, conf);
    mfma_gemm_kernel<0, true ><<<dim3(BATCH * NS / 64, 2), 256, 0, stream>>>(
        feat, wsrh, wsrl, bsr, xs, nullptr, nullptr);
    ln_kernel<<<BATCH * NS, DIMC, 0, stream>>>(xs, lng, lnb);
    mfma_gemm_kernel<1, false><<<dim3(BATCH * NS / 64, 2), 256, 0, stream>>>(
        xs, wkh, wkl, nullptr, nullptr, k16, nullptr);
    mfma_gemm_kernel<2, false><<<dim3(BATCH * NS / 64, 2), 256, 0, stream>>>(
        xs, wvh, wvl, nullptr, nullptr, vthi16, vtlo16);
    mfma_gemm_kernel<1, false><<<dim3(BATCH * NQ / 64, 2), 256, 0, stream>>>(
        x, wqh, wql, nullptr, nullptr, q16, nullptr);
    attn_mfma_kernel<<<BATCH * NHEADS * (NQ / 128), 256, 0, stream>>>(
        q16, k16, vthi16, vtlo16, conf, abuf);
    mfma_gemm_kernel<0, true ><<<dim3(BATCH * NQ / 64, 2), 256, 0, stream>>>(
        abuf, wph, wpl, bp, outp, nullptr, nullptr);
}